// Round 3
// baseline (499.891 us; speedup 1.0000x reference)
//
#include <hip/hip_runtime.h>
#include <hip/hip_bf16.h>

#define G_N 96
#define N_N 250
#define N_P 256
#define E_N 64
#define OUT_GSTRIDE (250 * 750)          // per-graph slab inside one output tensor (floats)
#define OUT_STRIDE  (96 * 250 * 750)     // 18,000,000 floats per output tensor

typedef __attribute__((ext_vector_type(4))) float floatx4;
typedef __attribute__((ext_vector_type(8))) short shortx8;

__device__ __forceinline__ float bf2f(unsigned short u) {
    union { unsigned int i; float f; } v; v.i = ((unsigned int)u) << 16; return v.f;
}
__device__ __forceinline__ unsigned short f2bf(float f) {
    union { float f; unsigned int i; } v; v.f = f;
    unsigned int x = v.i;
    return (unsigned short)((x + 0x7fffu + ((x >> 16) & 1u)) >> 16);  // RNE
}

// ---------------------------------------------------------------------------
// K1: nodevec = tanh(concat(hist,prior,obs) @ W + b)  -> bf16 [96][256][64]
// fp32 vector GEMM, 64x64 tile per block, 4x4 register blocking.
// Padded rows (n>=250) are written as zero so all downstream padding is zero.
// ---------------------------------------------------------------------------
__global__ __launch_bounds__(256) void k_embed(
    const float* __restrict__ hist, const float* __restrict__ prior,
    const float* __restrict__ obs, const float* __restrict__ Wemb,
    const float* __restrict__ bemb, unsigned short* __restrict__ nvb)
{
    __shared__ __attribute__((aligned(16))) float Xt[32][68];  // [k][n], pad 68
    __shared__ __attribute__((aligned(16))) float Wl[32][64];  // [k][e]
    const int t  = threadIdx.x;
    const int tx = t & 15, ty = t >> 4;
    const int rr0 = blockIdx.x * 64;   // padded row base; 64 | 256 so g uniform
    const int g   = rr0 >> 8;
    const int n0  = rr0 & 255;

    float acc[4][4] = {};

    for (int c = 0; c < 7; ++c) {      // 7 K-chunks of 32; source boundaries align
        const float* src; int rowlen, off;
        if (c < 4)      { src = hist;  rowlen = 128; off = c << 5; }
        else if (c < 6) { src = prior; rowlen = 64;  off = (c - 4) << 5; }
        else            { src = obs;   rowlen = 32;  off = 0; }
        __syncthreads();
        {   // stage X chunk transposed: 64 rows x 32 d
            const int d  = t & 31;
            const int nb = t >> 5;
            #pragma unroll
            for (int p = 0; p < 8; ++p) {
                const int nl = nb + p * 8;
                const int n  = n0 + nl;
                float v = 0.0f;
                if (n < N_N) v = src[(size_t)(g * N_N + n) * rowlen + off + d];
                Xt[d][nl] = v;
            }
        }
        {   // stage W chunk: 32 d x 64 e
            const int e  = t & 63;
            const int db = t >> 6;
            #pragma unroll
            for (int p = 0; p < 8; ++p) {
                const int dl = db + p * 4;
                Wl[dl][e] = Wemb[(c * 32 + dl) * 64 + e];
            }
        }
        __syncthreads();
        #pragma unroll
        for (int k = 0; k < 32; ++k) {
            const float4 av = *(const float4*)&Xt[k][4 * ty];
            const float4 bv = *(const float4*)&Wl[k][4 * tx];
            const float a[4] = {av.x, av.y, av.z, av.w};
            const float b[4] = {bv.x, bv.y, bv.z, bv.w};
            #pragma unroll
            for (int r = 0; r < 4; ++r)
                #pragma unroll
                for (int cc = 0; cc < 4; ++cc)
                    acc[r][cc] = fmaf(a[r], b[cc], acc[r][cc]);
        }
    }
    #pragma unroll
    for (int r = 0; r < 4; ++r) {
        const int nl = 4 * ty + r;
        const int n  = n0 + nl;
        unsigned short* d2 = nvb + ((size_t)g * N_P + (n0 + nl)) * E_N + 4 * tx;
        #pragma unroll
        for (int cc = 0; cc < 4; ++cc) {
            float v = 0.0f;
            if (n < N_N) v = tanhf(acc[r][cc] + bemb[4 * tx + cc]);
            d2[cc] = f2bf(v);
        }
    }
}

// ---------------------------------------------------------------------------
// K2a: S = relu(nv @ nv^T) per graph (bf16 MFMA 16x16x32, K=64) + fp32
// rowsums. Block owns 16 full rows (256 cols) -> rowsum needs no atomics.
// ---------------------------------------------------------------------------
__global__ __launch_bounds__(256) void k_sim(
    const unsigned short* __restrict__ nvb, unsigned short* __restrict__ Sb,
    float* __restrict__ rowsum)
{
    const int blk = blockIdx.x;          // 96*16
    const int g   = blk >> 4;
    const int i0  = (blk & 15) << 4;
    const int t    = threadIdx.x;
    const int w    = t >> 6;
    const int lane = t & 63;
    const int m = lane & 15, kg = lane >> 4;

    const shortx8* nvg = (const shortx8*)(nvb + (size_t)g * N_P * E_N);
    const shortx8 a0 = nvg[(i0 + m) * 8 + kg];       // k in [8kg, 8kg+8)
    const shortx8 a1 = nvg[(i0 + m) * 8 + 4 + kg];   // k in [32+8kg, ...)

    floatx4 acc[4];
    const floatx4 zero = {0.f, 0.f, 0.f, 0.f};
    #pragma unroll
    for (int tt = 0; tt < 4; ++tt) {
        const int j = (w << 6) + (tt << 4) + m;      // B-frag: n=lane&15, row-major nv
        const shortx8 b0 = nvg[j * 8 + kg];
        const shortx8 b1 = nvg[j * 8 + 4 + kg];
        floatx4 c = zero;
        c = __builtin_amdgcn_mfma_f32_16x16x32_bf16(a0, b0, c, 0, 0, 0);
        c = __builtin_amdgcn_mfma_f32_16x16x32_bf16(a1, b1, c, 0, 0, 0);
        acc[tt] = c;
    }

    float v[4] = {0.f, 0.f, 0.f, 0.f};
    unsigned short* Sg = Sb + (size_t)g * N_P * N_P;
    #pragma unroll
    for (int tt = 0; tt < 4; ++tt) {
        #pragma unroll
        for (int r = 0; r < 4; ++r) {
            float s = acc[tt][r];
            s = s > 0.f ? s : 0.f;                   // relu
            const int il = (kg << 2) + r;            // C/D: row=(lane>>4)*4+reg
            const int j  = (w << 6) + (tt << 4) + m; // col=lane&15
            Sg[(size_t)(i0 + il) * N_P + j] = f2bf(s);
            v[r] += s;
        }
    }
    #pragma unroll
    for (int r = 0; r < 4; ++r) {                    // reduce over m (16 lanes)
        v[r] += __shfl_xor(v[r], 1);
        v[r] += __shfl_xor(v[r], 2);
        v[r] += __shfl_xor(v[r], 4);
        v[r] += __shfl_xor(v[r], 8);
    }
    __shared__ float rs[4][16];
    if (m == 0) {
        #pragma unroll
        for (int r = 0; r < 4; ++r) rs[w][(kg << 2) + r] = v[r];
    }
    __syncthreads();
    if (t < 16) rowsum[g * N_P + i0 + t] = rs[0][t] + rs[1][t] + rs[2][t] + rs[3][t];
}

// ---------------------------------------------------------------------------
// K2b: t_i = sum_j S_ij d_j ; r=1/(d_i t_i+1e-9); c=r*d; w=c*d
// One row per thread, shortx8 vector loads. 96 blocks.
// ---------------------------------------------------------------------------
__global__ __launch_bounds__(256) void k_trans(
    const unsigned short* __restrict__ Sb, const float* __restrict__ rowsum,
    float* __restrict__ cArr, float* __restrict__ wArr)
{
    const int g = blockIdx.x;
    const int t = threadIdx.x;
    __shared__ __attribute__((aligned(16))) float dL[N_P];
    dL[t] = rsqrtf(rowsum[g * N_P + t] + 1e-9f);
    __syncthreads();
    const shortx8* row = (const shortx8*)(Sb + (size_t)g * N_P * N_P + (size_t)t * N_P);
    float a0 = 0.f, a1 = 0.f, a2 = 0.f, a3 = 0.f;
    #pragma unroll
    for (int ch = 0; ch < 32; ++ch) {
        const shortx8 sv = row[ch];
        const float4 d0 = *(const float4*)&dL[ch * 8];
        const float4 d1 = *(const float4*)&dL[ch * 8 + 4];
        a0 = fmaf(bf2f((unsigned short)sv[0]), d0.x, a0);
        a1 = fmaf(bf2f((unsigned short)sv[1]), d0.y, a1);
        a2 = fmaf(bf2f((unsigned short)sv[2]), d0.z, a2);
        a3 = fmaf(bf2f((unsigned short)sv[3]), d0.w, a3);
        a0 = fmaf(bf2f((unsigned short)sv[4]), d1.x, a0);
        a1 = fmaf(bf2f((unsigned short)sv[5]), d1.y, a1);
        a2 = fmaf(bf2f((unsigned short)sv[6]), d1.z, a2);
        a3 = fmaf(bf2f((unsigned short)sv[7]), d1.w, a3);
    }
    const float s  = (a0 + a1) + (a2 + a3);
    const float d  = dL[t];
    const float r  = 1.0f / (d * s + 1e-9f);
    const float c  = r * d;
    cArr[g * N_P + t] = c;
    wArr[g * N_P + t] = c * d;
}

// ---------------------------------------------------------------------------
// K2c: out0/out2 = (Dd S Dc)*mask tiled x3 (fp32, non-temporal stores)
// ---------------------------------------------------------------------------
__global__ __launch_bounds__(256) void k_out0(
    const unsigned short* __restrict__ Sb, const float* __restrict__ rowsum,
    const float* __restrict__ cArr, float* __restrict__ out)
{
    const int blk = blockIdx.x;          // 96*16
    const int g   = blk >> 4;
    const int i0  = (blk & 15) << 4;
    const int t   = threadIdx.x;
    __shared__ float cL[N_P];
    cL[t] = cArr[g * N_P + t];
    __syncthreads();
    const unsigned short* Sg = Sb + (size_t)g * N_P * N_P;
    float* o0 = out + (size_t)g * OUT_GSTRIDE;
    float* o2 = out + 2 * (size_t)OUT_STRIDE + (size_t)g * OUT_GSTRIDE;
    #pragma unroll 1
    for (int il = 0; il < 16; ++il) {
        const int i = i0 + il;
        const float dI = rsqrtf(rowsum[g * N_P + i] + 1e-9f);
        const float s  = bf2f(Sg[(size_t)i * N_P + t]);
        if (i < N_N && t < N_N) {
            const float p = (t == i) ? 0.f : dI * s * cL[t];
            const size_t base = (size_t)i * 750 + t;
            __builtin_nontemporal_store(p, o0 + base);
            __builtin_nontemporal_store(p, o0 + base + 250);
            __builtin_nontemporal_store(p, o0 + base + 500);
            __builtin_nontemporal_store(p, o2 + base);
            __builtin_nontemporal_store(p, o2 + base + 250);
            __builtin_nontemporal_store(p, o2 + base + 500);
        }
    }
}

// ---------------------------------------------------------------------------
// K3: M = (S*diag(w)) @ S^T per graph, w folded into the A-fragment after
// the LDS read (no SA buffer). Q = Dd M Dc ; out1/out3 = Q*mask tiled x3.
// ---------------------------------------------------------------------------
__global__ __launch_bounds__(256) void k_pp(
    const unsigned short* __restrict__ Sb, const float* __restrict__ rowsum,
    const float* __restrict__ cArr, const float* __restrict__ wArr,
    float* __restrict__ out)
{
    const int blk = blockIdx.x;          // 96*16
    const int g   = blk >> 4;
    const int i0  = ((blk >> 2) & 3) << 6;
    const int j0  = (blk & 3) << 6;
    const int t    = threadIdx.x;
    const int w    = t >> 6;
    const int lane = t & 63;
    const int m = lane & 15, kg = lane >> 4;

    __shared__ __attribute__((aligned(16))) unsigned short As[64][40]; // 80B stride
    __shared__ __attribute__((aligned(16))) unsigned short Bs[64][40];
    __shared__ float dRow[64], cCol[64];
    __shared__ __attribute__((aligned(16))) float wL[N_P];

    if (t < 64) dRow[t] = rsqrtf(rowsum[g * N_P + i0 + t] + 1e-9f);
    else if (t < 128) cCol[t - 64] = cArr[g * N_P + j0 + (t - 64)];
    wL[t] = wArr[g * N_P + t];

    const unsigned short* Sg = Sb + (size_t)g * N_P * N_P;

    floatx4 acc[4];
    const floatx4 zero = {0.f, 0.f, 0.f, 0.f};
    #pragma unroll
    for (int tt = 0; tt < 4; ++tt) acc[tt] = zero;

    const int sr = t >> 2, sc = t & 3;   // staging: 16B per thread per matrix
    for (int kb = 0; kb < 8; ++kb) {
        __syncthreads();
        *(uint4*)&As[sr][sc * 8] = *(const uint4*)(Sg + (size_t)(i0 + sr) * N_P + kb * 32 + sc * 8);
        *(uint4*)&Bs[sr][sc * 8] = *(const uint4*)(Sg + (size_t)(j0 + sr) * N_P + kb * 32 + sc * 8);
        __syncthreads();
        const shortx8 a = *(const shortx8*)&As[(w << 4) + m][kg << 3];
        const float4 w0 = *(const float4*)&wL[kb * 32 + (kg << 3)];
        const float4 w1 = *(const float4*)&wL[kb * 32 + (kg << 3) + 4];
        const float wv[8] = {w0.x, w0.y, w0.z, w0.w, w1.x, w1.y, w1.z, w1.w};
        shortx8 aw;
        #pragma unroll
        for (int u = 0; u < 8; ++u)
            aw[u] = (short)f2bf(bf2f((unsigned short)a[u]) * wv[u]);
        #pragma unroll
        for (int tt = 0; tt < 4; ++tt) {
            const shortx8 b = *(const shortx8*)&Bs[(tt << 4) + m][kg << 3];
            acc[tt] = __builtin_amdgcn_mfma_f32_16x16x32_bf16(aw, b, acc[tt], 0, 0, 0);
        }
    }

    float* o1 = out + (size_t)OUT_STRIDE + (size_t)g * OUT_GSTRIDE;
    float* o3 = out + 3 * (size_t)OUT_STRIDE + (size_t)g * OUT_GSTRIDE;
    #pragma unroll
    for (int tt = 0; tt < 4; ++tt) {
        #pragma unroll
        for (int r = 0; r < 4; ++r) {
            const int iL = (w << 4) + (kg << 2) + r;
            const int jL = (tt << 4) + m;
            const int I = i0 + iL, J = j0 + jL;
            if (I < N_N && J < N_N) {
                const float q = (I == J) ? 0.f : acc[tt][r] * dRow[iL] * cCol[jL];
                const size_t base = (size_t)I * 750 + J;
                __builtin_nontemporal_store(q, o1 + base);
                __builtin_nontemporal_store(q, o1 + base + 250);
                __builtin_nontemporal_store(q, o1 + base + 500);
                __builtin_nontemporal_store(q, o3 + base);
                __builtin_nontemporal_store(q, o3 + base + 250);
                __builtin_nontemporal_store(q, o3 + base + 500);
            }
        }
    }
}

extern "C" void kernel_launch(void* const* d_in, const int* in_sizes, int n_in,
                              void* d_out, int out_size, void* d_ws, size_t ws_size,
                              hipStream_t stream) {
    const float* hist  = (const float*)d_in[0];
    const float* prior = (const float*)d_in[1];
    const float* obs   = (const float*)d_in[2];
    const float* Wemb  = (const float*)d_in[3];
    const float* bemb  = (const float*)d_in[4];
    float* out = (float*)d_out;

    char* p = (char*)d_ws;
    unsigned short* nvb = (unsigned short*)p; p += (size_t)G_N * N_P * E_N * 2;   // 3.1 MB
    unsigned short* Sb  = (unsigned short*)p; p += (size_t)G_N * N_P * N_P * 2;   // 12.6 MB
    float* rowsum = (float*)p; p += (size_t)G_N * N_P * 4;
    float* cArr   = (float*)p; p += (size_t)G_N * N_P * 4;
    float* wArr   = (float*)p; p += (size_t)G_N * N_P * 4;
    // total ~16 MB of ws

    k_embed<<<dim3(G_N * N_P / 64), dim3(256), 0, stream>>>(hist, prior, obs, Wemb, bemb, nvb);
    k_sim  <<<dim3(G_N * 16),       dim3(256), 0, stream>>>(nvb, Sb, rowsum);
    k_trans<<<dim3(G_N),            dim3(256), 0, stream>>>(Sb, rowsum, cArr, wArr);
    k_out0 <<<dim3(G_N * 16),       dim3(256), 0, stream>>>(Sb, rowsum, cArr, out);
    k_pp   <<<dim3(G_N * 16),       dim3(256), 0, stream>>>(Sb, rowsum, cArr, wArr, out);
}

// Round 4
// 434.839 us; speedup vs baseline: 1.1496x; 1.1496x over previous
//
#include <hip/hip_runtime.h>
#include <hip/hip_bf16.h>

#define G_N 96
#define N_N 250
#define N_P 256
#define E_N 64
#define OUT_GSTRIDE (250 * 750)          // per-graph slab inside one output tensor (floats)
#define OUT_STRIDE  (96 * 250 * 750)     // 18,000,000 floats per output tensor

typedef __attribute__((ext_vector_type(4))) float floatx4;
typedef __attribute__((ext_vector_type(8))) short shortx8;

__device__ __forceinline__ float bf2f(unsigned short u) {
    union { unsigned int i; float f; } v; v.i = ((unsigned int)u) << 16; return v.f;
}
__device__ __forceinline__ unsigned short f2bf(float f) {
    union { float f; unsigned int i; } v; v.f = f;
    unsigned int x = v.i;
    return (unsigned short)((x + 0x7fffu + ((x >> 16) & 1u)) >> 16);  // RNE
}

// ---------------------------------------------------------------------------
// K1: nodevec = tanh(concat(hist,prior,obs) @ W + b)  -> bf16 [96][256][64]
// fp32 vector GEMM, 64x64 tile per block, 4x4 register blocking.
// Padded rows (n>=250) are written as zero so all downstream padding is zero.
// ---------------------------------------------------------------------------
__global__ __launch_bounds__(256) void k_embed(
    const float* __restrict__ hist, const float* __restrict__ prior,
    const float* __restrict__ obs, const float* __restrict__ Wemb,
    const float* __restrict__ bemb, unsigned short* __restrict__ nvb)
{
    __shared__ __attribute__((aligned(16))) float Xt[32][68];  // [k][n], pad 68
    __shared__ __attribute__((aligned(16))) float Wl[32][64];  // [k][e]
    const int t  = threadIdx.x;
    const int tx = t & 15, ty = t >> 4;
    const int rr0 = blockIdx.x * 64;   // padded row base; 64 | 256 so g uniform
    const int g   = rr0 >> 8;
    const int n0  = rr0 & 255;

    float acc[4][4] = {};

    for (int c = 0; c < 7; ++c) {      // 7 K-chunks of 32; source boundaries align
        const float* src; int rowlen, off;
        if (c < 4)      { src = hist;  rowlen = 128; off = c << 5; }
        else if (c < 6) { src = prior; rowlen = 64;  off = (c - 4) << 5; }
        else            { src = obs;   rowlen = 32;  off = 0; }
        __syncthreads();
        {   // stage X chunk transposed: 64 rows x 32 d
            const int d  = t & 31;
            const int nb = t >> 5;
            #pragma unroll
            for (int p = 0; p < 8; ++p) {
                const int nl = nb + p * 8;
                const int n  = n0 + nl;
                float v = 0.0f;
                if (n < N_N) v = src[(size_t)(g * N_N + n) * rowlen + off + d];
                Xt[d][nl] = v;
            }
        }
        {   // stage W chunk: 32 d x 64 e
            const int e  = t & 63;
            const int db = t >> 6;
            #pragma unroll
            for (int p = 0; p < 8; ++p) {
                const int dl = db + p * 4;
                Wl[dl][e] = Wemb[(c * 32 + dl) * 64 + e];
            }
        }
        __syncthreads();
        #pragma unroll
        for (int k = 0; k < 32; ++k) {
            const float4 av = *(const float4*)&Xt[k][4 * ty];
            const float4 bv = *(const float4*)&Wl[k][4 * tx];
            const float a[4] = {av.x, av.y, av.z, av.w};
            const float b[4] = {bv.x, bv.y, bv.z, bv.w};
            #pragma unroll
            for (int r = 0; r < 4; ++r)
                #pragma unroll
                for (int cc = 0; cc < 4; ++cc)
                    acc[r][cc] = fmaf(a[r], b[cc], acc[r][cc]);
        }
    }
    #pragma unroll
    for (int r = 0; r < 4; ++r) {
        const int nl = 4 * ty + r;
        const int n  = n0 + nl;
        unsigned short* d2 = nvb + ((size_t)g * N_P + (n0 + nl)) * E_N + 4 * tx;
        #pragma unroll
        for (int cc = 0; cc < 4; ++cc) {
            float v = 0.0f;
            if (n < N_N) v = tanhf(acc[r][cc] + bemb[4 * tx + cc]);
            d2[cc] = f2bf(v);
        }
    }
}

// ---------------------------------------------------------------------------
// K2a: S = relu(nv @ nv^T) per graph (bf16 MFMA 16x16x32, K=64) + fp32
// rowsums. Block owns 16 full rows (256 cols) -> rowsum needs no atomics.
// ---------------------------------------------------------------------------
__global__ __launch_bounds__(256) void k_sim(
    const unsigned short* __restrict__ nvb, unsigned short* __restrict__ Sb,
    float* __restrict__ rowsum)
{
    const int blk = blockIdx.x;          // 96*16
    const int g   = blk >> 4;
    const int i0  = (blk & 15) << 4;
    const int t    = threadIdx.x;
    const int w    = t >> 6;
    const int lane = t & 63;
    const int m = lane & 15, kg = lane >> 4;

    const shortx8* nvg = (const shortx8*)(nvb + (size_t)g * N_P * E_N);
    const shortx8 a0 = nvg[(i0 + m) * 8 + kg];       // k in [8kg, 8kg+8)
    const shortx8 a1 = nvg[(i0 + m) * 8 + 4 + kg];   // k in [32+8kg, ...)

    floatx4 acc[4];
    const floatx4 zero = {0.f, 0.f, 0.f, 0.f};
    #pragma unroll
    for (int tt = 0; tt < 4; ++tt) {
        const int j = (w << 6) + (tt << 4) + m;      // B-frag: n=lane&15, row-major nv
        const shortx8 b0 = nvg[j * 8 + kg];
        const shortx8 b1 = nvg[j * 8 + 4 + kg];
        floatx4 c = zero;
        c = __builtin_amdgcn_mfma_f32_16x16x32_bf16(a0, b0, c, 0, 0, 0);
        c = __builtin_amdgcn_mfma_f32_16x16x32_bf16(a1, b1, c, 0, 0, 0);
        acc[tt] = c;
    }

    float v[4] = {0.f, 0.f, 0.f, 0.f};
    unsigned short* Sg = Sb + (size_t)g * N_P * N_P;
    #pragma unroll
    for (int tt = 0; tt < 4; ++tt) {
        #pragma unroll
        for (int r = 0; r < 4; ++r) {
            float s = acc[tt][r];
            s = s > 0.f ? s : 0.f;                   // relu
            const int il = (kg << 2) + r;            // C/D: row=(lane>>4)*4+reg
            const int j  = (w << 6) + (tt << 4) + m; // col=lane&15
            Sg[(size_t)(i0 + il) * N_P + j] = f2bf(s);
            v[r] += s;
        }
    }
    #pragma unroll
    for (int r = 0; r < 4; ++r) {                    // reduce over m (16 lanes)
        v[r] += __shfl_xor(v[r], 1);
        v[r] += __shfl_xor(v[r], 2);
        v[r] += __shfl_xor(v[r], 4);
        v[r] += __shfl_xor(v[r], 8);
    }
    __shared__ float rs[4][16];
    if (m == 0) {
        #pragma unroll
        for (int r = 0; r < 4; ++r) rs[w][(kg << 2) + r] = v[r];
    }
    __syncthreads();
    if (t < 16) rowsum[g * N_P + i0 + t] = rs[0][t] + rs[1][t] + rs[2][t] + rs[3][t];
}

// ---------------------------------------------------------------------------
// K2b: t_i = sum_j S_ij d_j ; r=1/(d_i t_i+1e-9); c=r*d; w=c*d
// One row per thread, shortx8 vector loads. 96 blocks.
// ---------------------------------------------------------------------------
__global__ __launch_bounds__(256) void k_trans(
    const unsigned short* __restrict__ Sb, const float* __restrict__ rowsum,
    float* __restrict__ cArr, float* __restrict__ wArr)
{
    const int g = blockIdx.x;
    const int t = threadIdx.x;
    __shared__ __attribute__((aligned(16))) float dL[N_P];
    dL[t] = rsqrtf(rowsum[g * N_P + t] + 1e-9f);
    __syncthreads();
    const shortx8* row = (const shortx8*)(Sb + (size_t)g * N_P * N_P + (size_t)t * N_P);
    float a0 = 0.f, a1 = 0.f, a2 = 0.f, a3 = 0.f;
    #pragma unroll
    for (int ch = 0; ch < 32; ++ch) {
        const shortx8 sv = row[ch];
        const float4 d0 = *(const float4*)&dL[ch * 8];
        const float4 d1 = *(const float4*)&dL[ch * 8 + 4];
        a0 = fmaf(bf2f((unsigned short)sv[0]), d0.x, a0);
        a1 = fmaf(bf2f((unsigned short)sv[1]), d0.y, a1);
        a2 = fmaf(bf2f((unsigned short)sv[2]), d0.z, a2);
        a3 = fmaf(bf2f((unsigned short)sv[3]), d0.w, a3);
        a0 = fmaf(bf2f((unsigned short)sv[4]), d1.x, a0);
        a1 = fmaf(bf2f((unsigned short)sv[5]), d1.y, a1);
        a2 = fmaf(bf2f((unsigned short)sv[6]), d1.z, a2);
        a3 = fmaf(bf2f((unsigned short)sv[7]), d1.w, a3);
    }
    const float s  = (a0 + a1) + (a2 + a3);
    const float d  = dL[t];
    const float r  = 1.0f / (d * s + 1e-9f);
    const float c  = r * d;
    cArr[g * N_P + t] = c;
    wArr[g * N_P + t] = c * d;
}

// ---------------------------------------------------------------------------
// K2c: out0/out2 = (Dd S Dc)*mask tiled x3 (fp32, plain stores)
// ---------------------------------------------------------------------------
__global__ __launch_bounds__(256) void k_out0(
    const unsigned short* __restrict__ Sb, const float* __restrict__ rowsum,
    const float* __restrict__ cArr, float* __restrict__ out)
{
    const int blk = blockIdx.x;          // 96*16
    const int g   = blk >> 4;
    const int i0  = (blk & 15) << 4;
    const int t   = threadIdx.x;
    __shared__ float cL[N_P];
    cL[t] = cArr[g * N_P + t];
    __syncthreads();
    const unsigned short* Sg = Sb + (size_t)g * N_P * N_P;
    float* o0 = out + (size_t)g * OUT_GSTRIDE;
    float* o2 = out + 2 * (size_t)OUT_STRIDE + (size_t)g * OUT_GSTRIDE;
    #pragma unroll 1
    for (int il = 0; il < 16; ++il) {
        const int i = i0 + il;
        const float dI = rsqrtf(rowsum[g * N_P + i] + 1e-9f);
        const float s  = bf2f(Sg[(size_t)i * N_P + t]);
        if (i < N_N && t < N_N) {
            const float p = (t == i) ? 0.f : dI * s * cL[t];
            const size_t base = (size_t)i * 750 + t;
            o0[base] = p; o0[base + 250] = p; o0[base + 500] = p;
            o2[base] = p; o2[base + 250] = p; o2[base + 500] = p;
        }
    }
}

// ---------------------------------------------------------------------------
// K3: M = (S*diag(w)) @ S^T per graph, w folded into the A-fragment after
// the LDS read (no SA buffer). Q = Dd M Dc ; out1/out3 = Q*mask tiled x3.
// ---------------------------------------------------------------------------
__global__ __launch_bounds__(256) void k_pp(
    const unsigned short* __restrict__ Sb, const float* __restrict__ rowsum,
    const float* __restrict__ cArr, const float* __restrict__ wArr,
    float* __restrict__ out)
{
    const int blk = blockIdx.x;          // 96*16
    const int g   = blk >> 4;
    const int i0  = ((blk >> 2) & 3) << 6;
    const int j0  = (blk & 3) << 6;
    const int t    = threadIdx.x;
    const int w    = t >> 6;
    const int lane = t & 63;
    const int m = lane & 15, kg = lane >> 4;

    __shared__ __attribute__((aligned(16))) unsigned short As[64][40]; // 80B stride
    __shared__ __attribute__((aligned(16))) unsigned short Bs[64][40];
    __shared__ float dRow[64], cCol[64];
    __shared__ __attribute__((aligned(16))) float wL[N_P];

    if (t < 64) dRow[t] = rsqrtf(rowsum[g * N_P + i0 + t] + 1e-9f);
    else if (t < 128) cCol[t - 64] = cArr[g * N_P + j0 + (t - 64)];
    wL[t] = wArr[g * N_P + t];

    const unsigned short* Sg = Sb + (size_t)g * N_P * N_P;

    floatx4 acc[4];
    const floatx4 zero = {0.f, 0.f, 0.f, 0.f};
    #pragma unroll
    for (int tt = 0; tt < 4; ++tt) acc[tt] = zero;

    const int sr = t >> 2, sc = t & 3;   // staging: 16B per thread per matrix
    for (int kb = 0; kb < 8; ++kb) {
        __syncthreads();
        *(uint4*)&As[sr][sc * 8] = *(const uint4*)(Sg + (size_t)(i0 + sr) * N_P + kb * 32 + sc * 8);
        *(uint4*)&Bs[sr][sc * 8] = *(const uint4*)(Sg + (size_t)(j0 + sr) * N_P + kb * 32 + sc * 8);
        __syncthreads();
        const shortx8 a = *(const shortx8*)&As[(w << 4) + m][kg << 3];
        const float4 w0 = *(const float4*)&wL[kb * 32 + (kg << 3)];
        const float4 w1 = *(const float4*)&wL[kb * 32 + (kg << 3) + 4];
        const float wv[8] = {w0.x, w0.y, w0.z, w0.w, w1.x, w1.y, w1.z, w1.w};
        shortx8 aw;
        #pragma unroll
        for (int u = 0; u < 8; ++u)
            aw[u] = (short)f2bf(bf2f((unsigned short)a[u]) * wv[u]);
        #pragma unroll
        for (int tt = 0; tt < 4; ++tt) {
            const shortx8 b = *(const shortx8*)&Bs[(tt << 4) + m][kg << 3];
            acc[tt] = __builtin_amdgcn_mfma_f32_16x16x32_bf16(aw, b, acc[tt], 0, 0, 0);
        }
    }

    float* o1 = out + (size_t)OUT_STRIDE + (size_t)g * OUT_GSTRIDE;
    float* o3 = out + 3 * (size_t)OUT_STRIDE + (size_t)g * OUT_GSTRIDE;
    #pragma unroll
    for (int tt = 0; tt < 4; ++tt) {
        #pragma unroll
        for (int r = 0; r < 4; ++r) {
            const int iL = (w << 4) + (kg << 2) + r;
            const int jL = (tt << 4) + m;
            const int I = i0 + iL, J = j0 + jL;
            if (I < N_N && J < N_N) {
                const float q = (I == J) ? 0.f : acc[tt][r] * dRow[iL] * cCol[jL];
                const size_t base = (size_t)I * 750 + J;
                o1[base] = q; o1[base + 250] = q; o1[base + 500] = q;
                o3[base] = q; o3[base + 250] = q; o3[base + 500] = q;
            }
        }
    }
}

extern "C" void kernel_launch(void* const* d_in, const int* in_sizes, int n_in,
                              void* d_out, int out_size, void* d_ws, size_t ws_size,
                              hipStream_t stream) {
    const float* hist  = (const float*)d_in[0];
    const float* prior = (const float*)d_in[1];
    const float* obs   = (const float*)d_in[2];
    const float* Wemb  = (const float*)d_in[3];
    const float* bemb  = (const float*)d_in[4];
    float* out = (float*)d_out;

    char* p = (char*)d_ws;
    unsigned short* nvb = (unsigned short*)p; p += (size_t)G_N * N_P * E_N * 2;   // 3.1 MB
    unsigned short* Sb  = (unsigned short*)p; p += (size_t)G_N * N_P * N_P * 2;   // 12.6 MB
    float* rowsum = (float*)p; p += (size_t)G_N * N_P * 4;
    float* cArr   = (float*)p; p += (size_t)G_N * N_P * 4;
    float* wArr   = (float*)p; p += (size_t)G_N * N_P * 4;
    // total ~16 MB of ws

    k_embed<<<dim3(G_N * N_P / 64), dim3(256), 0, stream>>>(hist, prior, obs, Wemb, bemb, nvb);
    k_sim  <<<dim3(G_N * 16),       dim3(256), 0, stream>>>(nvb, Sb, rowsum);
    k_trans<<<dim3(G_N),            dim3(256), 0, stream>>>(Sb, rowsum, cArr, wArr);
    k_out0 <<<dim3(G_N * 16),       dim3(256), 0, stream>>>(Sb, rowsum, cArr, out);
    k_pp   <<<dim3(G_N * 16),       dim3(256), 0, stream>>>(Sb, rowsum, cArr, wArr, out);
}